// Round 3
// baseline (250.835 us; speedup 1.0000x reference)
//
#include <hip/hip_runtime.h>

// fbm_dropout, fused single-kernel, v2.1 (compile fix of v2).
//
// Semantics: zero columns of an (8192, 4096) fp32 matrix whose 64x64 grid
// cell is touched by any of the 6400 fiber points of the current epoch.
//
// Exact-equivalence note: for p in [0,1), u = p*64.0f is exact (power-of-2
// scale), floor(u) exact, and f = u - floor(u) is exact in fp32. So the
// reference's  x_low <= p && p <= x_high  is bit-identical to
// 0.25f <= f && f <= 0.75f  with cell = (int)floor(u).
//
// v2 changes vs v1 (87 us fused dispatch, 2.95 TB/s demand):
//  - NON-TEMPORAL output stores: out is write-once; letting it allocate in
//    L3 evicted half the (L3-resident) input each iteration (FETCH_SIZE was
//    exactly input/2). nt stores keep input fully L3-resident -> reads served
//    by L3, HBM carries only the write stream.
//  - contiguous 64 KB chunk per block (better HBM row locality than the
//    8 MB-strided sweep) with 4 loads batched before 4 stores (4 outstanding
//    loads/wave instead of 1).
//  - mask float4s for a thread cycle with period 4 in the chunk -> hoisted
//    into 4 registers, LDS read once.
// v2.1: __builtin_nontemporal_store needs a native vector type, not
//  HIP_vector_type<float,4> -> use ext_vector_type(4) float for the store.

#define N_COLS 4096
#define PTS_PER_EPOCH 100
#define N_GRID 64
#define TOTAL_PTS 10000
#define N_FIBERS 64
#define BLOCK 256
#define GRID_BLOCKS 2048          // 8 blocks/CU * 256 CUs, all co-resident
#define CHUNK4 4096               // float4s per block (64 KB): 2048*4096 = n4

typedef float f32x4 __attribute__((ext_vector_type(4)));

__global__ __launch_bounds__(BLOCK) void fused_fbm_dropout(
    const float* __restrict__ fx,
    const float* __restrict__ fy,
    const int* __restrict__ epoch_p,
    const f32x4* __restrict__ in4,
    f32x4* __restrict__ out4,
    int n4) {
    __shared__ float mask[N_COLS];          // 16 KB
    const int tid = threadIdx.x;

    // init mask to 1.0
    for (int i = tid; i < N_COLS; i += BLOCK) mask[i] = 1.0f;
    __syncthreads();

    // ---- phase 1: build mask in LDS (every block, redundant, L2-cached) ----
    const int t = epoch_p[0] * PTS_PER_EPOCH;   // multiple of 4 -> float4 aligned
    for (int g = tid; g < (N_FIBERS * PTS_PER_EPOCH) / 4; g += BLOCK) {
        const int f  = g / 25;
        const int j4 = g - f * 25;
        const int base4 = (f * TOTAL_PTS + t) / 4 + j4;
        const f32x4 px4 = ((const f32x4*)fx)[base4];
        const f32x4 py4 = ((const f32x4*)fy)[base4];
#pragma unroll
        for (int k = 0; k < 4; ++k) {
            const float ux = px4[k] * 64.0f;
            const float uy = py4[k] * 64.0f;
            const float gxf = floorf(ux);
            const float gyf = floorf(uy);
            const float frx = ux - gxf;   // exact
            const float fry = uy - gyf;   // exact
            if (frx >= 0.25f && frx <= 0.75f && fry >= 0.25f && fry <= 0.75f) {
                const int gx = (int)gxf;
                const int gy = (int)gyf;
                if (gx >= 0 && gx < N_GRID && gy >= 0 && gy < N_GRID) {
                    mask[gy * N_GRID + gx] = 0.0f;  // racing same-value: ok
                }
            }
        }
    }
    __syncthreads();

    // ---- phase 2: streaming apply over a contiguous 64 KB chunk ----
    const int base = blockIdx.x * CHUNK4;       // float4 index, mult of 4096
    // column of float4 i is i & 1023; i = base + k*256 + tid with base a
    // multiple of 4096 -> column = (k*256 + tid) & 1023, period 4 in k.
    f32x4 m[4];
#pragma unroll
    for (int k = 0; k < 4; ++k)
        m[k] = ((const f32x4*)mask)[(k * BLOCK + tid) & (N_COLS / 4 - 1)];

    if (base + CHUNK4 <= n4) {
        // fast path: exact-fit chunk, 4 rounds of {4 loads, 4 stores}
#pragma unroll
        for (int r = 0; r < 4; ++r) {
            f32x4 a[4];
#pragma unroll
            for (int c = 0; c < 4; ++c)
                a[c] = in4[base + (r * 4 + c) * BLOCK + tid];
#pragma unroll
            for (int c = 0; c < 4; ++c) {
                const f32x4 v = a[c] * m[c];
                __builtin_nontemporal_store(v, &out4[base + (r * 4 + c) * BLOCK + tid]);
            }
        }
    } else {
        // generic tail path (not taken for the 8192x4096 shape)
        for (int k = 0; k < CHUNK4 / BLOCK; ++k) {
            const int i = base + k * BLOCK + tid;
            if (i < n4) {
                const f32x4 v = in4[i] * m[k & 3];
                __builtin_nontemporal_store(v, &out4[i]);
            }
        }
    }
}

extern "C" void kernel_launch(void* const* d_in, const int* in_sizes, int n_in,
                              void* d_out, int out_size, void* d_ws, size_t ws_size,
                              hipStream_t stream) {
    const float* inp   = (const float*)d_in[0];   // (8192, 4096) fp32
    const float* fx    = (const float*)d_in[1];   // (64, 10000) fp32
    const float* fy    = (const float*)d_in[2];   // (64, 10000) fp32
    const int*   epoch = (const int*)d_in[3];     // scalar int

    const int n4 = out_size / 4;                  // 8,388,608 float4s
    fused_fbm_dropout<<<GRID_BLOCKS, BLOCK, 0, stream>>>(
        fx, fy, epoch, (const f32x4*)inp, (f32x4*)d_out, n4);
}

// Round 4
// 249.167 us; speedup vs baseline: 1.0067x; 1.0067x over previous
//
#include <hip/hip_runtime.h>

// fbm_dropout, fused single-kernel, v3.
//
// Semantics: zero columns of an (8192, 4096) fp32 matrix whose 64x64 grid
// cell is touched by any of the 6400 fiber points of the current epoch.
//
// Exact-equivalence note: for p in [0,1), u = p*64.0f is exact (power-of-2
// scale), floor(u) exact, and f = u - floor(u) is exact in fp32. So the
// reference's  x_low <= p && p <= x_high  is bit-identical to
// 0.25f <= f && f <= 0.75f  with cell = (int)floor(u).
//
// v3 vs v2.1 (93 us) / v1 (87 us):
//  - REVERT nt stores (FETCH_SIZE unchanged at 64 MB -> no L3 benefit; dur
//    regressed 87->93) and revert to v1's strided layout (per-thread mask
//    column invariant -> one mask register).
//  - Counter evidence says latency-bound, not BW-bound (HBM 27%, VALU 8%,
//    occ 54%): ~1 outstanding wave-load x ~17 waves ~= 17 KB in flight/CU,
//    below the ~20 KB Little's-law need for 6.3 TB/s. Fix: 8-deep static
//    software pipeline (8 KB in flight per wave).
//  - Issue the first 8 stream loads BEFORE the mask build, so phase 1's
//    VALU/L2 work runs under the shadow of in-flight HBM prefetches instead
//    of serially in front of the stream.

#define N_COLS 4096
#define PTS_PER_EPOCH 100
#define N_GRID 64
#define TOTAL_PTS 10000
#define N_FIBERS 64
#define BLOCK 256
#define GRID_BLOCKS 2048            // 8 blocks/CU * 256 CUs
#define STRIDE (GRID_BLOCKS * BLOCK)  // 524288 float4s; multiple of 1024
#define ITER 16                     // 8,388,608 / STRIDE
#define PF 8                        // prefetch depth (8 x f32x4 = 32 VGPR)

typedef float f32x4 __attribute__((ext_vector_type(4)));

__global__ __launch_bounds__(BLOCK) void fused_fbm_dropout(
    const float* __restrict__ fx,
    const float* __restrict__ fy,
    const int* __restrict__ epoch_p,
    const f32x4* __restrict__ in4,
    f32x4* __restrict__ out4,
    int n4) {
    __shared__ float mask[N_COLS];          // 16 KB
    const int tid = threadIdx.x;
    const int i0 = blockIdx.x * BLOCK + tid;
    const bool fast = (n4 == GRID_BLOCKS * BLOCK * ITER);

    // ---- phase 0: start the HBM stream immediately (8 loads in flight) ----
    f32x4 a[PF];
    if (fast) {
#pragma unroll
        for (int k = 0; k < PF; ++k) a[k] = in4[i0 + k * STRIDE];
    }

    // init mask to 1.0
    for (int i = tid; i < N_COLS; i += BLOCK) mask[i] = 1.0f;
    __syncthreads();

    // ---- phase 1: build mask in LDS (every block, redundant, L2-cached;
    //      runs under the shadow of the phase-0 prefetches) ----
    const int t = epoch_p[0] * PTS_PER_EPOCH;   // multiple of 4 -> f32x4 aligned
    for (int g = tid; g < (N_FIBERS * PTS_PER_EPOCH) / 4; g += BLOCK) {
        const int f  = g / 25;                  // magic-mul, 25 f32x4 per fiber
        const int j4 = g - f * 25;
        const int base4 = (f * TOTAL_PTS + t) / 4 + j4;
        const f32x4 px4 = ((const f32x4*)fx)[base4];
        const f32x4 py4 = ((const f32x4*)fy)[base4];
#pragma unroll
        for (int k = 0; k < 4; ++k) {
            const float ux = px4[k] * 64.0f;
            const float uy = py4[k] * 64.0f;
            const float gxf = floorf(ux);
            const float gyf = floorf(uy);
            const float frx = ux - gxf;   // exact
            const float fry = uy - gyf;   // exact
            if (frx >= 0.25f && frx <= 0.75f && fry >= 0.25f && fry <= 0.75f) {
                const int gx = (int)gxf;
                const int gy = (int)gyf;
                if (gx >= 0 && gx < N_GRID && gy >= 0 && gy < N_GRID) {
                    mask[gy * N_GRID + gx] = 0.0f;  // racing same-value: ok
                }
            }
        }
    }
    __syncthreads();

    // ---- phase 2: pipelined streaming apply ----
    // stride is a multiple of 1024 -> (i & 1023) loop-invariant per thread.
    const f32x4 m = ((const f32x4*)mask)[i0 & (N_COLS / 4 - 1)];

    if (fast) {
#pragma unroll
        for (int k = 0; k < ITER; ++k) {
            const f32x4 v = a[k & (PF - 1)] * m;          // waits on slot's load
            if (k + PF < ITER)
                a[k & (PF - 1)] = in4[i0 + (k + PF) * STRIDE];  // refill slot
            out4[i0 + k * STRIDE] = v;
        }
    } else {
        // generic fallback (not taken for the 8192x4096 shape)
        for (int i = i0; i < n4; i += STRIDE) {
            out4[i] = in4[i] * m;
        }
    }
}

extern "C" void kernel_launch(void* const* d_in, const int* in_sizes, int n_in,
                              void* d_out, int out_size, void* d_ws, size_t ws_size,
                              hipStream_t stream) {
    const float* inp   = (const float*)d_in[0];   // (8192, 4096) fp32
    const float* fx    = (const float*)d_in[1];   // (64, 10000) fp32
    const float* fy    = (const float*)d_in[2];   // (64, 10000) fp32
    const int*   epoch = (const int*)d_in[3];     // scalar int

    const int n4 = out_size / 4;                  // 8,388,608 float4s
    fused_fbm_dropout<<<GRID_BLOCKS, BLOCK, 0, stream>>>(
        fx, fy, epoch, (const f32x4*)inp, (f32x4*)d_out, n4);
}

// Round 6
// 245.069 us; speedup vs baseline: 1.0235x; 1.0167x over previous
//
#include <hip/hip_runtime.h>

// fbm_dropout, two-kernel v5 (= v4 with host-side out_size unit fix).
//
// Semantics: zero columns of an (8192, 4096) fp32 matrix whose 64x64 grid
// cell is touched by any of the 6400 fiber points of the current epoch.
//
// Exact-equivalence note: for p in [0,1), u = p*64.0f is exact (power-of-2
// scale), floor(u) exact, and f = u - floor(u) is exact in fp32. So the
// reference's  x_low <= p && p <= x_high  is bit-identical to
// 0.25f <= f && f <= 0.75f  with cell = (int)floor(u).
//
// Lessons baked in:
//  - out_size is an ELEMENT count (33,554,432 floats), not bytes. v4 divided
//    by 16 and silently wrote only 1/4 of the output. n4 = out_size / 4.
//  - Fused persistent-block versions (R1-R4) plateau at ~90 us for the
//    stream regardless of pipelining depth/layout; retire-style apply is
//    ~28 us faster. Two-kernel structure restored.
//  - build: f32x4 loads (3,200 instead of 12,800 scalar) on one CU.
//  - apply: 4 float4s per thread at stride q = n4/4 (8192 blocks instead of
//    32768): 4x fewer waves (launch rate), 4 loads in flight (MLP), and
//    q = 2,097,152 is a multiple of 1024 so all 4 elements of a thread
//    share one mask column -> single mask load per thread.

#define N_COLS 4096
#define PTS_PER_EPOCH 100
#define N_GRID 64
#define TOTAL_PTS 10000
#define N_FIBERS 64

typedef float f32x4 __attribute__((ext_vector_type(4)));

__global__ __launch_bounds__(1024) void build_mask_kernel(
    const float* __restrict__ fx,
    const float* __restrict__ fy,
    const int* __restrict__ epoch_p,
    float* __restrict__ mask) {
    const int tid = threadIdx.x;
    // init mask to 1.0 (d_ws is re-poisoned before every launch): one f32x4
    // store per thread covers 4096 floats with 1024 threads.
    ((f32x4*)mask)[tid] = (f32x4){1.0f, 1.0f, 1.0f, 1.0f};
    __syncthreads();

    const int t = epoch_p[0] * PTS_PER_EPOCH;    // multiple of 4 -> aligned
    // 6400 points = 1600 f32x4 groups per axis; 25 groups per fiber.
    for (int g = tid; g < (N_FIBERS * PTS_PER_EPOCH) / 4; g += 1024) {
        const int f  = g / 25;
        const int j4 = g - f * 25;
        const int base4 = (f * TOTAL_PTS + t) / 4 + j4;
        const f32x4 px4 = ((const f32x4*)fx)[base4];
        const f32x4 py4 = ((const f32x4*)fy)[base4];
#pragma unroll
        for (int k = 0; k < 4; ++k) {
            const float ux = px4[k] * 64.0f;
            const float uy = py4[k] * 64.0f;
            const float gxf = floorf(ux);
            const float gyf = floorf(uy);
            const float frx = ux - gxf;   // exact
            const float fry = uy - gyf;   // exact
            if (frx >= 0.25f && frx <= 0.75f && fry >= 0.25f && fry <= 0.75f) {
                const int gx = (int)gxf;
                const int gy = (int)gyf;
                if (gx >= 0 && gx < N_GRID && gy >= 0 && gy < N_GRID) {
                    mask[gy * N_GRID + gx] = 0.0f;  // racing same-value: ok
                }
            }
        }
    }
}

__global__ __launch_bounds__(256) void apply_mask_kernel(
    const f32x4* __restrict__ in4,
    const f32x4* __restrict__ mask4,
    f32x4* __restrict__ out4,
    int n4) {
    const int i0 = blockIdx.x * 256 + threadIdx.x;
    const int q = n4 >> 2;                       // 2,097,152 for this shape

    if (((q & (N_COLS / 4 - 1)) == 0) && (q << 2) == n4) {
        // fast path: q is a multiple of 1024 -> all 4 elements of this
        // thread share one mask column.
        if (i0 >= q) return;
        const f32x4 m = mask4[i0 & (N_COLS / 4 - 1)];
        const f32x4 a0 = in4[i0];
        const f32x4 a1 = in4[i0 + q];
        const f32x4 a2 = in4[i0 + 2 * q];
        const f32x4 a3 = in4[i0 + 3 * q];
        out4[i0]         = a0 * m;
        out4[i0 + q]     = a1 * m;
        out4[i0 + 2 * q] = a2 * m;
        out4[i0 + 3 * q] = a3 * m;
    } else {
        // generic fallback (not taken for the 8192x4096 shape)
        const int stride = gridDim.x * 256;
        for (int i = i0; i < n4; i += stride)
            out4[i] = in4[i] * mask4[i & (N_COLS / 4 - 1)];
    }
}

extern "C" void kernel_launch(void* const* d_in, const int* in_sizes, int n_in,
                              void* d_out, int out_size, void* d_ws, size_t ws_size,
                              hipStream_t stream) {
    const float* inp   = (const float*)d_in[0];   // (8192, 4096) fp32
    const float* fx    = (const float*)d_in[1];   // (64, 10000) fp32
    const float* fy    = (const float*)d_in[2];   // (64, 10000) fp32
    const int*   epoch = (const int*)d_in[3];     // scalar int
    float* mask = (float*)d_ws;                   // 4096 floats = 16 KB

    build_mask_kernel<<<1, 1024, 0, stream>>>(fx, fy, epoch, mask);

    // out_size is an ELEMENT count (floats): 33,554,432 for 8192x4096.
    const int n4 = out_size / 4;                  // 8,388,608 f32x4 elements
    const int q  = n4 >> 2;                       // 2,097,152 per k-slot
    const int grid = (q + 255) / 256;             // 8192 blocks
    apply_mask_kernel<<<grid, 256, 0, stream>>>(
        (const f32x4*)inp, (const f32x4*)d_ws, (f32x4*)d_out, n4);
}

// Round 7
// 235.737 us; speedup vs baseline: 1.0640x; 1.0396x over previous
//
#include <hip/hip_runtime.h>

// fbm_dropout, two-kernel v6 = R0 structure with vectorized build.
//
// Semantics: zero columns of an (8192, 4096) fp32 matrix whose 64x64 grid
// cell is touched by any of the 6400 fiber points of the current epoch.
//
// Exact-equivalence note: for p in [0,1), u = p*64.0f is exact (power-of-2
// scale), floor(u) exact, and f = u - floor(u) is exact in fp32. So the
// reference's  x_low <= p && p <= x_high  is bit-identical to
// 0.25f <= f && f <= 0.75f  with cell = (int)floor(u).
//
// Session lessons (R1-R5):
//  - out_size is an ELEMENT count (33,554,432 floats). n4 = out_size / 4.
//  - Every apply variant that spread the concurrently-active address window
//    (persistent 2048-block sweeps, 4-elem/thread at 32 MB stride) LOST
//    throughput vs the naive in-order retiring sweep (2.9-3.0 TB/s vs
//    ~4.4 TB/s demand). Keep R0's apply exactly: 1 float4/thread, 32768
//    blocks, compact sliding read+write windows.
//  - Build vectorized to f32x4 (3,200 loads vs 12,800 scalar) on one CU:
//    ~12 us -> ~3-4 us. Only delta vs R0.

#define N_COLS 4096
#define PTS_PER_EPOCH 100
#define N_GRID 64
#define TOTAL_PTS 10000
#define N_FIBERS 64

typedef float f32x4 __attribute__((ext_vector_type(4)));

__global__ __launch_bounds__(1024) void build_mask_kernel(
    const float* __restrict__ fx,
    const float* __restrict__ fy,
    const int* __restrict__ epoch_p,
    float* __restrict__ mask) {
    const int tid = threadIdx.x;
    // init mask to 1.0 (d_ws is re-poisoned before every launch): one f32x4
    // store per thread covers 4096 floats with 1024 threads.
    ((f32x4*)mask)[tid] = (f32x4){1.0f, 1.0f, 1.0f, 1.0f};
    __syncthreads();

    const int t = epoch_p[0] * PTS_PER_EPOCH;    // multiple of 4 -> aligned
    // 6400 points = 1600 f32x4 groups per axis; 25 groups per fiber.
    for (int g = tid; g < (N_FIBERS * PTS_PER_EPOCH) / 4; g += 1024) {
        const int f  = g / 25;
        const int j4 = g - f * 25;
        const int base4 = (f * TOTAL_PTS + t) / 4 + j4;
        const f32x4 px4 = ((const f32x4*)fx)[base4];
        const f32x4 py4 = ((const f32x4*)fy)[base4];
#pragma unroll
        for (int k = 0; k < 4; ++k) {
            const float ux = px4[k] * 64.0f;
            const float uy = py4[k] * 64.0f;
            const float gxf = floorf(ux);
            const float gyf = floorf(uy);
            const float frx = ux - gxf;   // exact
            const float fry = uy - gyf;   // exact
            if (frx >= 0.25f && frx <= 0.75f && fry >= 0.25f && fry <= 0.75f) {
                const int gx = (int)gxf;
                const int gy = (int)gyf;
                if (gx >= 0 && gx < N_GRID && gy >= 0 && gy < N_GRID) {
                    mask[gy * N_GRID + gx] = 0.0f;  // racing same-value: ok
                }
            }
        }
    }
}

__global__ void apply_mask_kernel(const f32x4* __restrict__ in4,
                                  const f32x4* __restrict__ mask4,
                                  f32x4* __restrict__ out4,
                                  int n4) {
    const int i = blockIdx.x * blockDim.x + threadIdx.x;
    if (i >= n4) return;
    const f32x4 a = in4[i];
    const f32x4 m = mask4[i & (N_COLS / 4 - 1)];  // 1024 float4s per row
    out4[i] = a * m;
}

extern "C" void kernel_launch(void* const* d_in, const int* in_sizes, int n_in,
                              void* d_out, int out_size, void* d_ws, size_t ws_size,
                              hipStream_t stream) {
    const float* inp   = (const float*)d_in[0];   // (8192, 4096) fp32
    const float* fx    = (const float*)d_in[1];   // (64, 10000) fp32
    const float* fy    = (const float*)d_in[2];   // (64, 10000) fp32
    const int*   epoch = (const int*)d_in[3];     // scalar int
    float* mask = (float*)d_ws;                   // 4096 floats = 16 KB

    build_mask_kernel<<<1, 1024, 0, stream>>>(fx, fy, epoch, mask);

    // out_size is an ELEMENT count (floats): 33,554,432 for 8192x4096.
    const int n4 = out_size / 4;                  // 8,388,608 f32x4 elements
    const int block = 256;
    const int grid = (n4 + block - 1) / block;    // 32768 blocks
    apply_mask_kernel<<<grid, block, 0, stream>>>(
        (const f32x4*)inp, (const f32x4*)d_ws, (f32x4*)d_out, n4);
}

// Round 8
// 234.670 us; speedup vs baseline: 1.0689x; 1.0045x over previous
//
#include <hip/hip_runtime.h>

// fbm_dropout, two-kernel v7: compact-chunk batched apply.
//
// Semantics: zero columns of an (8192, 4096) fp32 matrix whose 64x64 grid
// cell is touched by any of the 6400 fiber points of the current epoch.
//
// Exact-equivalence note: for p in [0,1), u = p*64.0f is exact (power-of-2
// scale), floor(u) exact, and f = u - floor(u) is exact in fp32. So the
// reference's  x_low <= p && p <= x_high  is bit-identical to
// 0.25f <= f && f <= 0.75f  with cell = (int)floor(u).
//
// Session schedule map (demand BW of the 256 MB stream):
//  - persistent 2048-block sweeps (any pipeline depth): 2.9 TB/s
//  - retiring, 4 elem/thread 32 MB apart:               3.0 TB/s
//  - retiring, 1 elem/thread (R0):                      4.4 TB/s
//  - copy ubench ceiling (read+write combined):         6.3 TB/s
// v7 tests the last untried cell: retiring + batched + COMPACT.
// Each block owns 1024 consecutive float4s (16 KB); each thread does 4
// elements 4 KB apart (per-instruction coalescing preserved, 4 loads
// issued back-to-back before any store). 8192 blocks, plain stores.
// out_size is an ELEMENT count: n4 = out_size / 4.

#define N_COLS 4096
#define PTS_PER_EPOCH 100
#define N_GRID 64
#define TOTAL_PTS 10000
#define N_FIBERS 64
#define CHUNK4 1024   // float4s per block

typedef float f32x4 __attribute__((ext_vector_type(4)));

__global__ __launch_bounds__(1024) void build_mask_kernel(
    const float* __restrict__ fx,
    const float* __restrict__ fy,
    const int* __restrict__ epoch_p,
    float* __restrict__ mask) {
    const int tid = threadIdx.x;
    // init mask to 1.0 (d_ws is re-poisoned before every launch)
    ((f32x4*)mask)[tid] = (f32x4){1.0f, 1.0f, 1.0f, 1.0f};
    __syncthreads();

    const int t = epoch_p[0] * PTS_PER_EPOCH;    // multiple of 4 -> aligned
    // 6400 points = 1600 f32x4 groups per axis; 25 groups per fiber.
    for (int g = tid; g < (N_FIBERS * PTS_PER_EPOCH) / 4; g += 1024) {
        const int f  = g / 25;
        const int j4 = g - f * 25;
        const int base4 = (f * TOTAL_PTS + t) / 4 + j4;
        const f32x4 px4 = ((const f32x4*)fx)[base4];
        const f32x4 py4 = ((const f32x4*)fy)[base4];
#pragma unroll
        for (int k = 0; k < 4; ++k) {
            const float ux = px4[k] * 64.0f;
            const float uy = py4[k] * 64.0f;
            const float gxf = floorf(ux);
            const float gyf = floorf(uy);
            const float frx = ux - gxf;   // exact
            const float fry = uy - gyf;   // exact
            if (frx >= 0.25f && frx <= 0.75f && fry >= 0.25f && fry <= 0.75f) {
                const int gx = (int)gxf;
                const int gy = (int)gyf;
                if (gx >= 0 && gx < N_GRID && gy >= 0 && gy < N_GRID) {
                    mask[gy * N_GRID + gx] = 0.0f;  // racing same-value: ok
                }
            }
        }
    }
}

__global__ __launch_bounds__(256) void apply_mask_kernel(
    const f32x4* __restrict__ in4,
    const f32x4* __restrict__ mask4,
    f32x4* __restrict__ out4,
    int n4) {
    const int tid  = threadIdx.x;
    const int base = blockIdx.x * CHUNK4;

    if (base + CHUNK4 <= n4 && (n4 & (CHUNK4 - 1)) == 0) {
        // fast path: full 16 KB chunk. base is a multiple of 1024 (= float4s
        // per row), so column of element (base + off) is off & 1023 -> the
        // mask indices are block-invariant, k*256+tid.
        f32x4 a[4];
#pragma unroll
        for (int k = 0; k < 4; ++k) a[k] = in4[base + k * 256 + tid];
        f32x4 m[4];
#pragma unroll
        for (int k = 0; k < 4; ++k) m[k] = mask4[k * 256 + tid];
#pragma unroll
        for (int k = 0; k < 4; ++k) out4[base + k * 256 + tid] = a[k] * m[k];
    } else {
        // generic tail (not taken for the 8192x4096 shape)
        for (int i = base + tid; i < n4 && i < base + CHUNK4; i += 256)
            out4[i] = in4[i] * mask4[i & (N_COLS / 4 - 1)];
    }
}

extern "C" void kernel_launch(void* const* d_in, const int* in_sizes, int n_in,
                              void* d_out, int out_size, void* d_ws, size_t ws_size,
                              hipStream_t stream) {
    const float* inp   = (const float*)d_in[0];   // (8192, 4096) fp32
    const float* fx    = (const float*)d_in[1];   // (64, 10000) fp32
    const float* fy    = (const float*)d_in[2];   // (64, 10000) fp32
    const int*   epoch = (const int*)d_in[3];     // scalar int
    float* mask = (float*)d_ws;                   // 4096 floats = 16 KB

    build_mask_kernel<<<1, 1024, 0, stream>>>(fx, fy, epoch, mask);

    // out_size is an ELEMENT count (floats): 33,554,432 for 8192x4096.
    const int n4 = out_size / 4;                  // 8,388,608 f32x4 elements
    const int grid = (n4 + CHUNK4 - 1) / CHUNK4;  // 8192 blocks
    apply_mask_kernel<<<grid, 256, 0, stream>>>(
        (const f32x4*)inp, (const f32x4*)d_ws, (f32x4*)d_out, n4);
}